// Round 7
// baseline (219.298 us; speedup 1.0000x reference)
//
#include <hip/hip_runtime.h>
#include <hip/hip_bf16.h>
#include <math.h>

#define EN 8192
#define EL 8192
#define D  256
#define NG 64
#define INF_BITS 0x7f800000u

typedef __attribute__((ext_vector_type(8))) short  bf16x8;
typedef __attribute__((ext_vector_type(4))) float  f32x4;

__device__ __forceinline__ unsigned short f2bf(float f) {
    unsigned u = __float_as_uint(f);
    unsigned r = (u + 0x7fffu + ((u >> 16) & 1u)) >> 16;   // RNE
    return (unsigned short)r;
}

// ---------------- kernel 1: fused init + edge features ----------------
__global__ void prep(const float* __restrict__ h,
                     const int* __restrict__ node_edge,
                     const int* __restrict__ label_edge,
                     unsigned short* __restrict__ efn, float* __restrict__ normN,
                     unsigned short* __restrict__ efl, float* __restrict__ normL,
                     unsigned* __restrict__ inf_buf)
{
    int b = blockIdx.x;
    if (b < 1024) {
        uint4 v = make_uint4(INF_BITS, INF_BITS, INF_BITS, INF_BITS);
        ((uint4*)inf_buf)[b * 256 + threadIdx.x] = v;
        return;
    }
    b -= 1024;
    const int* edges; unsigned short* ef; float* norm;
    if (b < 2048) { edges = node_edge;  ef = efn; norm = normN; }
    else          { b -= 2048; edges = label_edge; ef = efl; norm = normL; }

    int wave = threadIdx.x >> 6;
    int lane = threadIdx.x & 63;
    int e = b * 4 + wave;
    int a  = edges[e];
    int bb = edges[EN + e];          // En == El == 8192
    float4 va = ((const float4*)(h + (size_t)a  * D))[lane];
    float4 vb = ((const float4*)(h + (size_t)bb * D))[lane];
    float4 f;
    f.x = 0.5f * (va.x + vb.x);
    f.y = 0.5f * (va.y + vb.y);
    f.z = 0.5f * (va.z + vb.z);
    f.w = 0.5f * (va.w + vb.w);
    float sq = f.x*f.x + f.y*f.y + f.z*f.z + f.w*f.w;
    ushort4 pk;
    pk.x = f2bf(f.x); pk.y = f2bf(f.y); pk.z = f2bf(f.z); pk.w = f2bf(f.w);
    ((ushort4*)(ef + (size_t)e * D))[lane] = pk;
    #pragma unroll
    for (int off = 1; off < 64; off <<= 1)
        sq += __shfl_xor(sq, off, 64);
    if (lane == 0) norm[e] = sq;
}

// ---------------- kernel 2: fused GEMM + sq-distance + segmented min ----------------
// Restructured K-loop (R6 was latency-bound: MfmaUtil 15%, VALU 34%, HBM 11%,
// nothing saturated):
//  * A-operand entirely in REGISTERS: afr[2][8] (64 VGPR), loaded once per
//    block, direct global->VGPR in MFMA A-frag layout A[m=lc][k=quad*8+j].
//    No A staging, no A ds_reads, no A barrier dependency.
//  * B double-buffered in LDS (2 x 16 KB): stage(k+2) issued right after the
//    barrier retiring buf readers -> a full compute phase overlaps the load
//    latency before the compiler's vmcnt(0)-at-barrier drain. 5 barriers
//    per block (was 8), each with real overlap.
//  * B XOR-swizzle (phys granule cc holds global cc^(col&7)) -> 0 bank
//    conflicts (verified R4). Epilogue identical to R6 (verified): wave-
//    uniform fast paths, squared-dist min, bulk atomics, sqrt in finalize.
__launch_bounds__(512, 4)
__global__ void dist_min(const unsigned short* __restrict__ A,   // ef_n [EN][D]
                         const unsigned short* __restrict__ B,   // ef_l [EL][D]
                         const float* __restrict__ normN,
                         const float* __restrict__ normL,
                         const int* __restrict__ node_batch,
                         const int* __restrict__ label_batch,
                         unsigned* __restrict__ bufN,  // [EN][NG] min sq-dist bits
                         unsigned* __restrict__ bufL)  // [NG][EL] min sq-dist bits
{
    __shared__ unsigned short Bs[2][128 * 64];

    const int tid  = threadIdx.x;
    const int lane = tid & 63;
    const int wave = tid >> 6;          // 0..7
    const int quad = lane >> 4;
    const int lc   = lane & 15;
    const int m0   = blockIdx.y * 128;
    const int n0   = blockIdx.x * 128;
    const int wr   = (wave >> 1) * 32;  // 4 row groups of 32
    const int wc   = (wave & 1) * 64;   // 2 col groups of 64

    // ---- A fragments: direct global->register, full K=256 ----
    bf16x8 afr[2][8];                   // [row-tile][k-tile(32)]
    #pragma unroll
    for (int mi = 0; mi < 2; ++mi) {
        const unsigned short* rp =
            A + (size_t)(m0 + wr + mi*16 + lc) * D + quad*8;
        #pragma unroll
        for (int kt = 0; kt < 8; ++kt)
            afr[mi][kt] = *(const bf16x8*)(rp + kt*32);
    }

    f32x4 acc[2][4];
    #pragma unroll
    for (int i = 0; i < 2; ++i)
        #pragma unroll
        for (int j = 0; j < 4; ++j) {
            f32x4 z = {0.f, 0.f, 0.f, 0.f};
            acc[i][j] = z;
        }

    // stage B k-slab kts (64 k) into Bs[buf]; swizzled granules
    auto stageB = [&](int kts, int buf) {
        #pragma unroll
        for (int t = 0; t < 2; ++t) {
            int c = t * 512 + tid;              // 1024 granules: 128 cols x 8
            int col = c >> 3, cc = c & 7;
            int scc = cc ^ (col & 7);
            const unsigned short* gp =
                B + (size_t)(n0 + col) * D + kts * 64 + scc * 8;
            __builtin_amdgcn_global_load_lds(
                (const __attribute__((address_space(1))) void*)gp,
                (__attribute__((address_space(3))) void*)
                    (&Bs[buf][col * 64 + cc * 8]), 16, 0, 0);
        }
    };

    stageB(0, 0);
    stageB(1, 1);
    __syncthreads();                    // drains stage(0),(1) + afr loads

    for (int kts = 0; kts < 4; ++kts) { // K = 256 = 4 slabs of 64
        const int buf = kts & 1;
        #pragma unroll
        for (int kk = 0; kk < 2; ++kk) {
            bf16x8 bfv[4];
            #pragma unroll
            for (int ni = 0; ni < 4; ++ni)
                bfv[ni] = *(const bf16x8*)(&Bs[buf][(wc + ni*16 + lc) * 64
                                                   + ((kk*4 + quad) ^ (lc & 7)) * 8]);
            #pragma unroll
            for (int mi = 0; mi < 2; ++mi)
                #pragma unroll
                for (int ni = 0; ni < 4; ++ni)
                    acc[mi][ni] = __builtin_amdgcn_mfma_f32_16x16x32_bf16(
                        afr[mi][kts*2 + kk], bfv[ni], acc[mi][ni], 0, 0, 0);
        }
        __syncthreads();                // retires buf readers; drains in-flight stage
        if (kts < 2) stageB(kts + 2, buf);  // refill just-retired buffer
    }

    // ---- epilogue (verified R6) ----
    float nb[4]; int gl[4];
    #pragma unroll
    for (int ni = 0; ni < 4; ++ni) {
        int col = n0 + wc + ni*16 + lc;
        nb[ni] = normL[col];
        gl[ni] = label_batch[col];
    }
    float na[8]; int gr[8];
    #pragma unroll
    for (int mi = 0; mi < 2; ++mi)
        #pragma unroll
        for (int r = 0; r < 4; ++r) {
            int row = m0 + wr + mi*16 + quad*4 + r;
            na[mi*4 + r] = normN[row];
            gr[mi*4 + r] = node_batch[row];
        }

    #pragma unroll
    for (int mi = 0; mi < 2; ++mi)
        #pragma unroll
        for (int ni = 0; ni < 4; ++ni)
            #pragma unroll
            for (int r = 0; r < 4; ++r)
                acc[mi][ni][r] = fmaxf(
                    fmaf(-2.0f, acc[mi][ni][r], na[mi*4 + r] + nb[ni]), 0.0f);

    const float FINF = __uint_as_float(INF_BITS);

    // per-row min over columns, grouped by label graph; wave cols [n0+wc, +63]
    int glo = label_batch[n0 + wc], ghi = label_batch[n0 + wc + 63];
    if (glo == ghi) {
        float rm[8];
        #pragma unroll
        for (int mi = 0; mi < 2; ++mi)
            #pragma unroll
            for (int r = 0; r < 4; ++r) {
                float m = fminf(fminf(acc[mi][0][r], acc[mi][1][r]),
                                fminf(acc[mi][2][r], acc[mi][3][r]));
                m = fminf(m, __shfl_xor(m, 1, 64));
                m = fminf(m, __shfl_xor(m, 2, 64));
                m = fminf(m, __shfl_xor(m, 4, 64));
                m = fminf(m, __shfl_xor(m, 8, 64));
                rm[mi*4 + r] = m;
            }
        if (lc == 0) {
            #pragma unroll
            for (int mi = 0; mi < 2; ++mi)
                #pragma unroll
                for (int r = 0; r < 4; ++r) {
                    int row = m0 + wr + mi*16 + quad*4 + r;
                    atomicMin(&bufN[row * NG + glo], __float_as_uint(rm[mi*4 + r]));
                }
        }
    } else {
        for (int g = glo; g <= ghi; ++g) {
            bool s0 = (gl[0] == g), s1 = (gl[1] == g), s2 = (gl[2] == g), s3 = (gl[3] == g);
            float rm[8];
            #pragma unroll
            for (int mi = 0; mi < 2; ++mi)
                #pragma unroll
                for (int r = 0; r < 4; ++r) {
                    float m = s0 ? acc[mi][0][r] : FINF;
                    m = fminf(m, s1 ? acc[mi][1][r] : FINF);
                    m = fminf(m, s2 ? acc[mi][2][r] : FINF);
                    m = fminf(m, s3 ? acc[mi][3][r] : FINF);
                    m = fminf(m, __shfl_xor(m, 1, 64));
                    m = fminf(m, __shfl_xor(m, 2, 64));
                    m = fminf(m, __shfl_xor(m, 4, 64));
                    m = fminf(m, __shfl_xor(m, 8, 64));
                    rm[mi*4 + r] = m;
                }
            if (lc == 0) {
                #pragma unroll
                for (int mi = 0; mi < 2; ++mi)
                    #pragma unroll
                    for (int r = 0; r < 4; ++r) {
                        int row = m0 + wr + mi*16 + quad*4 + r;
                        atomicMin(&bufN[row * NG + g], __float_as_uint(rm[mi*4 + r]));
                    }
            }
        }
    }

    // per-col min over rows, grouped by node graph; wave rows [m0+wr, +31]
    int rlo = node_batch[m0 + wr], rhi = node_batch[m0 + wr + 31];
    if (rlo == rhi) {
        float cm[4];
        #pragma unroll
        for (int ni = 0; ni < 4; ++ni) {
            float m = acc[0][ni][0];
            m = fminf(m, acc[0][ni][1]); m = fminf(m, acc[0][ni][2]);
            m = fminf(m, acc[0][ni][3]); m = fminf(m, acc[1][ni][0]);
            m = fminf(m, acc[1][ni][1]); m = fminf(m, acc[1][ni][2]);
            m = fminf(m, acc[1][ni][3]);
            m = fminf(m, __shfl_xor(m, 16, 64));
            m = fminf(m, __shfl_xor(m, 32, 64));
            cm[ni] = m;
        }
        if (quad == 0) {
            #pragma unroll
            for (int ni = 0; ni < 4; ++ni) {
                int col = n0 + wc + ni*16 + lc;
                atomicMin(&bufL[rlo * EL + col], __float_as_uint(cm[ni]));
            }
        }
    } else {
        for (int g = rlo; g <= rhi; ++g) {
            float cm[4];
            #pragma unroll
            for (int ni = 0; ni < 4; ++ni) {
                float m = FINF;
                #pragma unroll
                for (int mi = 0; mi < 2; ++mi)
                    #pragma unroll
                    for (int r = 0; r < 4; ++r)
                        m = fminf(m, (gr[mi*4 + r] == g) ? acc[mi][ni][r] : FINF);
                m = fminf(m, __shfl_xor(m, 16, 64));
                m = fminf(m, __shfl_xor(m, 32, 64));
                cm[ni] = m;
            }
            if (quad == 0) {
                #pragma unroll
                for (int ni = 0; ni < 4; ++ni) {
                    int col = n0 + wc + ni*16 + lc;
                    atomicMin(&bufL[g * EL + col], __float_as_uint(cm[ni]));
                }
            }
        }
    }
}

// ---------------- kernel 3: segment means + combine ----------------
__device__ __forceinline__ int lbound(const int* __restrict__ a, int n, int v) {
    int lo = 0, hi = n;
    while (lo < hi) { int mid = (lo + hi) >> 1; if (a[mid] < v) lo = mid + 1; else hi = mid; }
    return lo;
}

// one block per node-graph gn; MUST be launched with 1024 threads
__global__ void finalize(const unsigned* __restrict__ bufN,
                         const unsigned* __restrict__ bufL,
                         const int* __restrict__ node_batch,
                         const int* __restrict__ label_batch,
                         float* __restrict__ out)
{
    __shared__ float sN[NG];   // sum over rows of -dist, per label graph
    __shared__ float sL[NG];   // sum over cols of -dist, per label graph
    int gn  = blockIdx.x;
    int tid = threadIdx.x;
    if (tid < NG) { sN[tid] = 0.0f; sL[tid] = 0.0f; }
    __syncthreads();

    int ns = lbound(node_batch, EN, gn);
    int ne = lbound(node_batch, EN, gn + 1);

    {
        int t = tid & 63, strip = tid >> 6;          // 16 row strips
        float acc = 0.0f;
        for (int i = ns + strip; i < ne; i += 16) {
            unsigned b = bufN[i * NG + t];
            if (b != INF_BITS) acc -= sqrtf(__uint_as_float(b));
        }
        atomicAdd(&sN[t], acc);
    }

    for (int j = tid; j < EL; j += 1024) {
        unsigned b = bufL[gn * EL + j];
        if (b != INF_BITS) {
            int g = label_batch[j];
            atomicAdd(&sL[g], -sqrtf(__uint_as_float(b)));
        }
    }
    __syncthreads();

    if (tid < NG) {
        int t = tid;
        int cn = ne - ns;
        int ls = lbound(label_batch, EL, t);
        int le = lbound(label_batch, EL, t + 1);
        int cl = le - ls;
        float out_n = sN[t] / (float)(cn > 0 ? cn : 1);
        float out_l = sL[t] / (float)(cl > 0 ? cl : 1);
        out[gn * NG + t] = 0.5f * (out_n + out_l);
    }
}

extern "C" void kernel_launch(void* const* d_in, const int* in_sizes, int n_in,
                              void* d_out, int out_size, void* d_ws, size_t ws_size,
                              hipStream_t stream)
{
    const float* h          = (const float*)d_in[0];
    const int* node_edge    = (const int*)d_in[1];
    const int* node_batch   = (const int*)d_in[2];
    const int* label_edge   = (const int*)d_in[3];
    const int* label_batch  = (const int*)d_in[4];
    float* out = (float*)d_out;

    char* ws = (char*)d_ws;
    unsigned short* efn = (unsigned short*)ws; ws += (size_t)EN * D * 2;
    unsigned short* efl = (unsigned short*)ws; ws += (size_t)EL * D * 2;
    float* normN = (float*)ws;                 ws += (size_t)EN * 4;
    float* normL = (float*)ws;                 ws += (size_t)EL * 4;
    unsigned* bufN = (unsigned*)ws;            ws += (size_t)EN * NG * 4;
    unsigned* bufL = (unsigned*)ws;            ws += (size_t)NG * EL * 4;

    // bufN,bufL contiguous: 1024 init blocks + 2048 + 2048 edge blocks
    prep<<<5120, 256, 0, stream>>>(h, node_edge, label_edge,
                                   efn, normN, efl, normL, bufN);
    dist_min<<<dim3(EL / 128, EN / 128), 512, 0, stream>>>(
        efn, efl, normN, normL, node_batch, label_batch, bufN, bufL);
    finalize<<<NG, 1024, 0, stream>>>(bufN, bufL, node_batch, label_batch, out);
}

// Round 9
// 204.230 us; speedup vs baseline: 1.0738x; 1.0738x over previous
//
#include <hip/hip_runtime.h>
#include <hip/hip_bf16.h>
#include <math.h>

#define EN 8192
#define EL 8192
#define D  256
#define NG 64
#define INF_BITS 0x7f800000u

typedef __attribute__((ext_vector_type(8))) short  bf16x8;
typedef __attribute__((ext_vector_type(4))) float  f32x4;

__device__ __forceinline__ unsigned short f2bf(float f) {
    unsigned u = __float_as_uint(f);
    unsigned r = (u + 0x7fffu + ((u >> 16) & 1u)) >> 16;   // RNE
    return (unsigned short)r;
}

// ---------------- kernel 1: fused init + edge features ----------------
__global__ void prep(const float* __restrict__ h,
                     const int* __restrict__ node_edge,
                     const int* __restrict__ label_edge,
                     unsigned short* __restrict__ efn, float* __restrict__ normN,
                     unsigned short* __restrict__ efl, float* __restrict__ normL,
                     unsigned* __restrict__ inf_buf)
{
    int b = blockIdx.x;
    if (b < 1024) {
        uint4 v = make_uint4(INF_BITS, INF_BITS, INF_BITS, INF_BITS);
        ((uint4*)inf_buf)[b * 256 + threadIdx.x] = v;
        return;
    }
    b -= 1024;
    const int* edges; unsigned short* ef; float* norm;
    if (b < 2048) { edges = node_edge;  ef = efn; norm = normN; }
    else          { b -= 2048; edges = label_edge; ef = efl; norm = normL; }

    int wave = threadIdx.x >> 6;
    int lane = threadIdx.x & 63;
    int e = b * 4 + wave;
    int a  = edges[e];
    int bb = edges[EN + e];          // En == El == 8192
    float4 va = ((const float4*)(h + (size_t)a  * D))[lane];
    float4 vb = ((const float4*)(h + (size_t)bb * D))[lane];
    float4 f;
    f.x = 0.5f * (va.x + vb.x);
    f.y = 0.5f * (va.y + vb.y);
    f.z = 0.5f * (va.z + vb.z);
    f.w = 0.5f * (va.w + vb.w);
    float sq = f.x*f.x + f.y*f.y + f.z*f.z + f.w*f.w;
    ushort4 pk;
    pk.x = f2bf(f.x); pk.y = f2bf(f.y); pk.z = f2bf(f.z); pk.w = f2bf(f.w);
    ((ushort4*)(ef + (size_t)e * D))[lane] = pk;
    #pragma unroll
    for (int off = 1; off < 64; off <<= 1)
        sq += __shfl_xor(sq, off, 64);
    if (lane == 0) norm[e] = sq;
}

// ---------------- kernel 2: fused GEMM + sq-distance + segmented min ----------------
// Register-A + double-buffered-B structure in a SAFE config (R8's (512,2)
// variant core-dumped; R7 proved the code body numerically correct):
//  * 256 threads (4 waves), block tile 64 rows x 128 cols, wave-tile 32x64
//    (identical per-wave workload + epilogue to the verified R6/R7).
//  * launch_bounds(256,4): VGPR cap 128 -> afr[2][8] (64 VGPR) stays
//    resident (R7's (512,4) capped at 64 VGPR and re-issued A loads in-loop).
//    4 blocks/CU x 4 waves = 16 waves/CU (50% ceiling).
//  * A-operand direct global->VGPR once per block, MFMA A-frag layout
//    A[m=lc][k=quad*8+j] (numerics verified in R7).
//  * B double-buffered in LDS (2 x 16 KB): stage(k+2) issued right after the
//    barrier retiring buf -> full compute phase overlaps the load before the
//    vmcnt(0)-at-barrier drain. XOR-swizzle -> 0 bank conflicts (R4).
__launch_bounds__(256, 4)
__global__ void dist_min(const unsigned short* __restrict__ A,   // ef_n [EN][D]
                         const unsigned short* __restrict__ B,   // ef_l [EL][D]
                         const float* __restrict__ normN,
                         const float* __restrict__ normL,
                         const int* __restrict__ node_batch,
                         const int* __restrict__ label_batch,
                         unsigned* __restrict__ bufN,  // [EN][NG] min sq-dist bits
                         unsigned* __restrict__ bufL)  // [NG][EL] min sq-dist bits
{
    __shared__ unsigned short Bs[2][128 * 64];

    const int tid  = threadIdx.x;
    const int lane = tid & 63;
    const int wave = tid >> 6;          // 0..3
    const int quad = lane >> 4;
    const int lc   = lane & 15;
    const int m0   = blockIdx.y * 64;
    const int n0   = blockIdx.x * 128;
    const int wr   = (wave >> 1) * 32;  // 2 row groups of 32
    const int wc   = (wave & 1) * 64;   // 2 col groups of 64

    // stage B k-slab kts (64 k) into Bs[buf]; swizzled granules
    auto stageB = [&](int kts, int buf) {
        #pragma unroll
        for (int t = 0; t < 4; ++t) {
            int c = t * 256 + tid;              // 1024 granules: 128 cols x 8
            int col = c >> 3, cc = c & 7;
            int scc = cc ^ (col & 7);
            const unsigned short* gp =
                B + (size_t)(n0 + col) * D + kts * 64 + scc * 8;
            __builtin_amdgcn_global_load_lds(
                (const __attribute__((address_space(1))) void*)gp,
                (__attribute__((address_space(3))) void*)
                    (&Bs[buf][col * 64 + cc * 8]), 16, 0, 0);
        }
    };

    stageB(0, 0);
    stageB(1, 1);

    // ---- A fragments: direct global->register, full K=256 ----
    bf16x8 afr[2][8];                   // [row-tile][k-step(32)]
    #pragma unroll
    for (int mi = 0; mi < 2; ++mi) {
        const unsigned short* rp =
            A + (size_t)(m0 + wr + mi*16 + lc) * D + quad*8;
        #pragma unroll
        for (int kt = 0; kt < 8; ++kt)
            afr[mi][kt] = *(const bf16x8*)(rp + kt*32);
    }

    f32x4 acc[2][4];
    #pragma unroll
    for (int i = 0; i < 2; ++i)
        #pragma unroll
        for (int j = 0; j < 4; ++j) {
            f32x4 z = {0.f, 0.f, 0.f, 0.f};
            acc[i][j] = z;
        }

    __syncthreads();                    // drains stage(0),(1) + afr loads

    for (int kts = 0; kts < 4; ++kts) { // K = 256 = 4 slabs of 64
        const int buf = kts & 1;
        #pragma unroll
        for (int kk = 0; kk < 2; ++kk) {
            bf16x8 bfv[4];
            #pragma unroll
            for (int ni = 0; ni < 4; ++ni)
                bfv[ni] = *(const bf16x8*)(&Bs[buf][(wc + ni*16 + lc) * 64
                                                   + ((kk*4 + quad) ^ (lc & 7)) * 8]);
            #pragma unroll
            for (int mi = 0; mi < 2; ++mi)
                #pragma unroll
                for (int ni = 0; ni < 4; ++ni)
                    acc[mi][ni] = __builtin_amdgcn_mfma_f32_16x16x32_bf16(
                        afr[mi][kts*2 + kk], bfv[ni], acc[mi][ni], 0, 0, 0);
        }
        __syncthreads();                // retires buf readers; drains in-flight stage
        if (kts < 2) stageB(kts + 2, buf);  // refill just-retired buffer
    }

    // ---- epilogue (verified R6/R7) ----
    float nb[4]; int gl[4];
    #pragma unroll
    for (int ni = 0; ni < 4; ++ni) {
        int col = n0 + wc + ni*16 + lc;
        nb[ni] = normL[col];
        gl[ni] = label_batch[col];
    }
    float na[8]; int gr[8];
    #pragma unroll
    for (int mi = 0; mi < 2; ++mi)
        #pragma unroll
        for (int r = 0; r < 4; ++r) {
            int row = m0 + wr + mi*16 + quad*4 + r;
            na[mi*4 + r] = normN[row];
            gr[mi*4 + r] = node_batch[row];
        }

    #pragma unroll
    for (int mi = 0; mi < 2; ++mi)
        #pragma unroll
        for (int ni = 0; ni < 4; ++ni)
            #pragma unroll
            for (int r = 0; r < 4; ++r)
                acc[mi][ni][r] = fmaxf(
                    fmaf(-2.0f, acc[mi][ni][r], na[mi*4 + r] + nb[ni]), 0.0f);

    const float FINF = __uint_as_float(INF_BITS);

    // per-row min over columns, grouped by label graph; wave cols [n0+wc, +63]
    int glo = label_batch[n0 + wc], ghi = label_batch[n0 + wc + 63];
    if (glo == ghi) {
        float rm[8];
        #pragma unroll
        for (int mi = 0; mi < 2; ++mi)
            #pragma unroll
            for (int r = 0; r < 4; ++r) {
                float m = fminf(fminf(acc[mi][0][r], acc[mi][1][r]),
                                fminf(acc[mi][2][r], acc[mi][3][r]));
                m = fminf(m, __shfl_xor(m, 1, 64));
                m = fminf(m, __shfl_xor(m, 2, 64));
                m = fminf(m, __shfl_xor(m, 4, 64));
                m = fminf(m, __shfl_xor(m, 8, 64));
                rm[mi*4 + r] = m;
            }
        if (lc == 0) {
            #pragma unroll
            for (int mi = 0; mi < 2; ++mi)
                #pragma unroll
                for (int r = 0; r < 4; ++r) {
                    int row = m0 + wr + mi*16 + quad*4 + r;
                    atomicMin(&bufN[row * NG + glo], __float_as_uint(rm[mi*4 + r]));
                }
        }
    } else {
        for (int g = glo; g <= ghi; ++g) {
            bool s0 = (gl[0] == g), s1 = (gl[1] == g), s2 = (gl[2] == g), s3 = (gl[3] == g);
            float rm[8];
            #pragma unroll
            for (int mi = 0; mi < 2; ++mi)
                #pragma unroll
                for (int r = 0; r < 4; ++r) {
                    float m = s0 ? acc[mi][0][r] : FINF;
                    m = fminf(m, s1 ? acc[mi][1][r] : FINF);
                    m = fminf(m, s2 ? acc[mi][2][r] : FINF);
                    m = fminf(m, s3 ? acc[mi][3][r] : FINF);
                    m = fminf(m, __shfl_xor(m, 1, 64));
                    m = fminf(m, __shfl_xor(m, 2, 64));
                    m = fminf(m, __shfl_xor(m, 4, 64));
                    m = fminf(m, __shfl_xor(m, 8, 64));
                    rm[mi*4 + r] = m;
                }
            if (lc == 0) {
                #pragma unroll
                for (int mi = 0; mi < 2; ++mi)
                    #pragma unroll
                    for (int r = 0; r < 4; ++r) {
                        int row = m0 + wr + mi*16 + quad*4 + r;
                        atomicMin(&bufN[row * NG + g], __float_as_uint(rm[mi*4 + r]));
                    }
            }
        }
    }

    // per-col min over rows, grouped by node graph; wave rows [m0+wr, +31]
    int rlo = node_batch[m0 + wr], rhi = node_batch[m0 + wr + 31];
    if (rlo == rhi) {
        float cm[4];
        #pragma unroll
        for (int ni = 0; ni < 4; ++ni) {
            float m = acc[0][ni][0];
            m = fminf(m, acc[0][ni][1]); m = fminf(m, acc[0][ni][2]);
            m = fminf(m, acc[0][ni][3]); m = fminf(m, acc[1][ni][0]);
            m = fminf(m, acc[1][ni][1]); m = fminf(m, acc[1][ni][2]);
            m = fminf(m, acc[1][ni][3]);
            m = fminf(m, __shfl_xor(m, 16, 64));
            m = fminf(m, __shfl_xor(m, 32, 64));
            cm[ni] = m;
        }
        if (quad == 0) {
            #pragma unroll
            for (int ni = 0; ni < 4; ++ni) {
                int col = n0 + wc + ni*16 + lc;
                atomicMin(&bufL[rlo * EL + col], __float_as_uint(cm[ni]));
            }
        }
    } else {
        for (int g = rlo; g <= rhi; ++g) {
            float cm[4];
            #pragma unroll
            for (int ni = 0; ni < 4; ++ni) {
                float m = FINF;
                #pragma unroll
                for (int mi = 0; mi < 2; ++mi)
                    #pragma unroll
                    for (int r = 0; r < 4; ++r)
                        m = fminf(m, (gr[mi*4 + r] == g) ? acc[mi][ni][r] : FINF);
                m = fminf(m, __shfl_xor(m, 16, 64));
                m = fminf(m, __shfl_xor(m, 32, 64));
                cm[ni] = m;
            }
            if (quad == 0) {
                #pragma unroll
                for (int ni = 0; ni < 4; ++ni) {
                    int col = n0 + wc + ni*16 + lc;
                    atomicMin(&bufL[g * EL + col], __float_as_uint(cm[ni]));
                }
            }
        }
    }
}

// ---------------- kernel 3: segment means + combine ----------------
__device__ __forceinline__ int lbound(const int* __restrict__ a, int n, int v) {
    int lo = 0, hi = n;
    while (lo < hi) { int mid = (lo + hi) >> 1; if (a[mid] < v) lo = mid + 1; else hi = mid; }
    return lo;
}

// one block per node-graph gn; MUST be launched with 1024 threads
__global__ void finalize(const unsigned* __restrict__ bufN,
                         const unsigned* __restrict__ bufL,
                         const int* __restrict__ node_batch,
                         const int* __restrict__ label_batch,
                         float* __restrict__ out)
{
    __shared__ float sN[NG];   // sum over rows of -dist, per label graph
    __shared__ float sL[NG];   // sum over cols of -dist, per label graph
    int gn  = blockIdx.x;
    int tid = threadIdx.x;
    if (tid < NG) { sN[tid] = 0.0f; sL[tid] = 0.0f; }
    __syncthreads();

    int ns = lbound(node_batch, EN, gn);
    int ne = lbound(node_batch, EN, gn + 1);

    {
        int t = tid & 63, strip = tid >> 6;          // 16 row strips
        float acc = 0.0f;
        for (int i = ns + strip; i < ne; i += 16) {
            unsigned b = bufN[i * NG + t];
            if (b != INF_BITS) acc -= sqrtf(__uint_as_float(b));
        }
        atomicAdd(&sN[t], acc);
    }

    for (int j = tid; j < EL; j += 1024) {
        unsigned b = bufL[gn * EL + j];
        if (b != INF_BITS) {
            int g = label_batch[j];
            atomicAdd(&sL[g], -sqrtf(__uint_as_float(b)));
        }
    }
    __syncthreads();

    if (tid < NG) {
        int t = tid;
        int cn = ne - ns;
        int ls = lbound(label_batch, EL, t);
        int le = lbound(label_batch, EL, t + 1);
        int cl = le - ls;
        float out_n = sN[t] / (float)(cn > 0 ? cn : 1);
        float out_l = sL[t] / (float)(cl > 0 ? cl : 1);
        out[gn * NG + t] = 0.5f * (out_n + out_l);
    }
}

extern "C" void kernel_launch(void* const* d_in, const int* in_sizes, int n_in,
                              void* d_out, int out_size, void* d_ws, size_t ws_size,
                              hipStream_t stream)
{
    const float* h          = (const float*)d_in[0];
    const int* node_edge    = (const int*)d_in[1];
    const int* node_batch   = (const int*)d_in[2];
    const int* label_edge   = (const int*)d_in[3];
    const int* label_batch  = (const int*)d_in[4];
    float* out = (float*)d_out;

    char* ws = (char*)d_ws;
    unsigned short* efn = (unsigned short*)ws; ws += (size_t)EN * D * 2;
    unsigned short* efl = (unsigned short*)ws; ws += (size_t)EL * D * 2;
    float* normN = (float*)ws;                 ws += (size_t)EN * 4;
    float* normL = (float*)ws;                 ws += (size_t)EL * 4;
    unsigned* bufN = (unsigned*)ws;            ws += (size_t)EN * NG * 4;
    unsigned* bufL = (unsigned*)ws;            ws += (size_t)NG * EL * 4;

    // bufN,bufL contiguous: 1024 init blocks + 2048 + 2048 edge blocks
    prep<<<5120, 256, 0, stream>>>(h, node_edge, label_edge,
                                   efn, normN, efl, normL, bufN);
    dist_min<<<dim3(EL / 128, EN / 64), 256, 0, stream>>>(
        efn, efl, normN, normL, node_batch, label_batch, bufN, bufL);
    finalize<<<NG, 1024, 0, stream>>>(bufN, bufL, node_batch, label_batch, out);
}

// Round 10
// 200.818 us; speedup vs baseline: 1.0920x; 1.0170x over previous
//
#include <hip/hip_runtime.h>
#include <hip/hip_bf16.h>
#include <math.h>

#define EN 8192
#define EL 8192
#define D  256
#define NG 64
#define INF_BITS 0x7f800000u

typedef __attribute__((ext_vector_type(8))) short  bf16x8;
typedef __attribute__((ext_vector_type(4))) float  f32x4;

__device__ __forceinline__ unsigned short f2bf(float f) {
    unsigned u = __float_as_uint(f);
    unsigned r = (u + 0x7fffu + ((u >> 16) & 1u)) >> 16;   // RNE
    return (unsigned short)r;
}

// ---------------- kernel 1: fused init + edge features ----------------
__global__ void prep(const float* __restrict__ h,
                     const int* __restrict__ node_edge,
                     const int* __restrict__ label_edge,
                     unsigned short* __restrict__ efn, float* __restrict__ normN,
                     unsigned short* __restrict__ efl, float* __restrict__ normL,
                     unsigned* __restrict__ inf_buf)
{
    int b = blockIdx.x;
    if (b < 1024) {
        uint4 v = make_uint4(INF_BITS, INF_BITS, INF_BITS, INF_BITS);
        ((uint4*)inf_buf)[b * 256 + threadIdx.x] = v;
        return;
    }
    b -= 1024;
    const int* edges; unsigned short* ef; float* norm;
    if (b < 2048) { edges = node_edge;  ef = efn; norm = normN; }
    else          { b -= 2048; edges = label_edge; ef = efl; norm = normL; }

    int wave = threadIdx.x >> 6;
    int lane = threadIdx.x & 63;
    int e = b * 4 + wave;
    int a  = edges[e];
    int bb = edges[EN + e];          // En == El == 8192
    float4 va = ((const float4*)(h + (size_t)a  * D))[lane];
    float4 vb = ((const float4*)(h + (size_t)bb * D))[lane];
    float4 f;
    f.x = 0.5f * (va.x + vb.x);
    f.y = 0.5f * (va.y + vb.y);
    f.z = 0.5f * (va.z + vb.z);
    f.w = 0.5f * (va.w + vb.w);
    float sq = f.x*f.x + f.y*f.y + f.z*f.z + f.w*f.w;
    ushort4 pk;
    pk.x = f2bf(f.x); pk.y = f2bf(f.y); pk.z = f2bf(f.z); pk.w = f2bf(f.w);
    ((ushort4*)(ef + (size_t)e * D))[lane] = pk;
    #pragma unroll
    for (int off = 1; off < 64; off <<= 1)
        sq += __shfl_xor(sq, off, 64);
    if (lane == 0) norm[e] = sq;
}

// ---------------- kernel 2: fused GEMM + sq-distance + segmented min ----------------
// Row-band pipeline (register-A falsified R7/R9: allocator re-issues A loads;
// R6's 4-step K-loop has no overlap depth):
//  * block = 128 rows x 2048 cols (grid 64 bands x 4 chunks = 256 = 1/CU);
//    chunk = blockIdx&3 -> per-XCD working set ~3MB <= 4MB L2.
//  * A band staged to LDS ONCE (128x256, 64 KB): A traffic /16, A reads never
//    re-wait on staging.
//  * B double-buffered (2x32 KB, BK=128), 32-step pipeline:
//    compute(buf); sync; stageB(step+2 -> buf) -- each stage has a full
//    compute phase in flight before the vmcnt(0)-at-barrier drain.
//  * XOR-swizzle on As and Bs (verified 0 conflicts R4-R9): phys granule =
//    logical ^ (row&7); reader row/col low bits = lc&7.
//  * Epilogue = R6/R9-verified code per col-tile; row-side (na/gr/rlo/rhi)
//    hoisted out of the ct loop. sqrt deferred to finalize.
__launch_bounds__(512, 2)
__global__ void dist_min(const unsigned short* __restrict__ A,   // ef_n [EN][D]
                         const unsigned short* __restrict__ B,   // ef_l [EL][D]
                         const float* __restrict__ normN,
                         const float* __restrict__ normL,
                         const int* __restrict__ node_batch,
                         const int* __restrict__ label_batch,
                         unsigned* __restrict__ bufN,  // [EN][NG] min sq-dist bits
                         unsigned* __restrict__ bufL)  // [NG][EL] min sq-dist bits
{
    __shared__ unsigned short As[128 * 256];     // 64 KB, whole K
    __shared__ unsigned short Bs[2][128 * 128];  // 2 x 32 KB, BK=128 slabs

    const int tid  = threadIdx.x;
    const int lane = tid & 63;
    const int wave = tid >> 6;          // 0..7
    const int quad = lane >> 4;
    const int lc   = lane & 15;
    const int m0   = (blockIdx.x >> 2) * 128;    // row band
    const int cb   = (blockIdx.x & 3) * 2048;    // col chunk base
    const int wr   = (wave >> 1) * 32;  // 4 row groups of 32
    const int wc   = (wave & 1) * 64;   // 2 col groups of 64

    // ---- stage A band once: 4096 granules (16 B), swizzled ----
    #pragma unroll
    for (int t = 0; t < 8; ++t) {
        int c = t * 512 + tid;
        int row = c >> 5, g = c & 31;            // 32 granules per 256-k row
        const unsigned short* gp =
            A + (size_t)(m0 + row) * D + (g ^ (row & 7)) * 8;
        __builtin_amdgcn_global_load_lds(
            (const __attribute__((address_space(1))) void*)gp,
            (__attribute__((address_space(3))) void*)(As + row * 256 + g * 8),
            16, 0, 0);
    }

    // stage B pipeline-step slab: ct = step>>1, k-slab s = step&1
    auto stageB = [&](int step) {
        int ct = step >> 1, s = step & 1;
        unsigned short* bs = Bs[step & 1];
        #pragma unroll
        for (int t = 0; t < 4; ++t) {
            int c = t * 512 + tid;
            int col = c >> 4, g = c & 15;        // 16 granules per 128-k row
            const unsigned short* gp =
                B + (size_t)(cb + ct * 128 + col) * D + s * 128
                  + (g ^ (col & 7)) * 8;
            __builtin_amdgcn_global_load_lds(
                (const __attribute__((address_space(1))) void*)gp,
                (__attribute__((address_space(3))) void*)(bs + col * 128 + g * 8),
                16, 0, 0);
        }
    };
    stageB(0);
    stageB(1);

    // ---- hoisted row-side epilogue data (constant over ct) ----
    float na[8]; int gr[8];
    #pragma unroll
    for (int mi = 0; mi < 2; ++mi)
        #pragma unroll
        for (int r = 0; r < 4; ++r) {
            int row = m0 + wr + mi*16 + quad*4 + r;
            na[mi*4 + r] = normN[row];
            gr[mi*4 + r] = node_batch[row];
        }
    const int rlo = node_batch[m0 + wr], rhi = node_batch[m0 + wr + 31];
    const float FINF = __uint_as_float(INF_BITS);

    f32x4 acc[2][4];
    #pragma unroll
    for (int i = 0; i < 2; ++i)
        #pragma unroll
        for (int j = 0; j < 4; ++j) {
            f32x4 z = {0.f, 0.f, 0.f, 0.f};
            acc[i][j] = z;
        }

    __syncthreads();                    // drains A + first two B slabs

    for (int step = 0; step < 32; ++step) {      // 16 col-tiles x 2 k-slabs
        const int s = step & 1;
        const unsigned short* bs = Bs[s];
        #pragma unroll
        for (int kk = 0; kk < 4; ++kk) {         // 4 x k32 per 128-slab
            bf16x8 af[2], bfv[4];
            #pragma unroll
            for (int mi = 0; mi < 2; ++mi)
                af[mi] = *(const bf16x8*)(As + (wr + mi*16 + lc) * 256
                                             + ((s*16 + kk*4 + quad) ^ (lc & 7)) * 8);
            #pragma unroll
            for (int ni = 0; ni < 4; ++ni)
                bfv[ni] = *(const bf16x8*)(bs + (wc + ni*16 + lc) * 128
                                              + ((kk*4 + quad) ^ (lc & 7)) * 8);
            #pragma unroll
            for (int mi = 0; mi < 2; ++mi)
                #pragma unroll
                for (int ni = 0; ni < 4; ++ni)
                    acc[mi][ni] = __builtin_amdgcn_mfma_f32_16x16x32_bf16(
                        af[mi], bfv[ni], acc[mi][ni], 0, 0, 0);
        }
        __syncthreads();                // retires Bs[s] readers + drains in-flight ops
        if (step + 2 < 32) stageB(step + 2);     // refill just-retired buffer

        if (s == 1) {
            // ---- epilogue for col-tile ct (verified R6/R9) ----
            const int ct = step >> 1;
            const int n0 = cb + ct * 128;

            float nb[4]; int gl[4];
            #pragma unroll
            for (int ni = 0; ni < 4; ++ni) {
                int col = n0 + wc + ni*16 + lc;
                nb[ni] = normL[col];
                gl[ni] = label_batch[col];
            }

            #pragma unroll
            for (int mi = 0; mi < 2; ++mi)
                #pragma unroll
                for (int ni = 0; ni < 4; ++ni)
                    #pragma unroll
                    for (int r = 0; r < 4; ++r)
                        acc[mi][ni][r] = fmaxf(
                            fmaf(-2.0f, acc[mi][ni][r], na[mi*4 + r] + nb[ni]), 0.0f);

            // per-row min over cols by label graph; wave cols [n0+wc, +63]
            int glo = label_batch[n0 + wc], ghi = label_batch[n0 + wc + 63];
            if (glo == ghi) {
                float rm[8];
                #pragma unroll
                for (int mi = 0; mi < 2; ++mi)
                    #pragma unroll
                    for (int r = 0; r < 4; ++r) {
                        float m = fminf(fminf(acc[mi][0][r], acc[mi][1][r]),
                                        fminf(acc[mi][2][r], acc[mi][3][r]));
                        m = fminf(m, __shfl_xor(m, 1, 64));
                        m = fminf(m, __shfl_xor(m, 2, 64));
                        m = fminf(m, __shfl_xor(m, 4, 64));
                        m = fminf(m, __shfl_xor(m, 8, 64));
                        rm[mi*4 + r] = m;
                    }
                if (lc == 0) {
                    #pragma unroll
                    for (int mi = 0; mi < 2; ++mi)
                        #pragma unroll
                        for (int r = 0; r < 4; ++r) {
                            int row = m0 + wr + mi*16 + quad*4 + r;
                            atomicMin(&bufN[row * NG + glo],
                                      __float_as_uint(rm[mi*4 + r]));
                        }
                }
            } else {
                for (int g = glo; g <= ghi; ++g) {
                    bool s0 = (gl[0] == g), s1 = (gl[1] == g),
                         s2 = (gl[2] == g), s3 = (gl[3] == g);
                    float rm[8];
                    #pragma unroll
                    for (int mi = 0; mi < 2; ++mi)
                        #pragma unroll
                        for (int r = 0; r < 4; ++r) {
                            float m = s0 ? acc[mi][0][r] : FINF;
                            m = fminf(m, s1 ? acc[mi][1][r] : FINF);
                            m = fminf(m, s2 ? acc[mi][2][r] : FINF);
                            m = fminf(m, s3 ? acc[mi][3][r] : FINF);
                            m = fminf(m, __shfl_xor(m, 1, 64));
                            m = fminf(m, __shfl_xor(m, 2, 64));
                            m = fminf(m, __shfl_xor(m, 4, 64));
                            m = fminf(m, __shfl_xor(m, 8, 64));
                            rm[mi*4 + r] = m;
                        }
                    if (lc == 0) {
                        #pragma unroll
                        for (int mi = 0; mi < 2; ++mi)
                            #pragma unroll
                            for (int r = 0; r < 4; ++r) {
                                int row = m0 + wr + mi*16 + quad*4 + r;
                                atomicMin(&bufN[row * NG + g],
                                          __float_as_uint(rm[mi*4 + r]));
                            }
                    }
                }
            }

            // per-col min over rows by node graph; wave rows [m0+wr, +31]
            if (rlo == rhi) {
                float cm[4];
                #pragma unroll
                for (int ni = 0; ni < 4; ++ni) {
                    float m = acc[0][ni][0];
                    m = fminf(m, acc[0][ni][1]); m = fminf(m, acc[0][ni][2]);
                    m = fminf(m, acc[0][ni][3]); m = fminf(m, acc[1][ni][0]);
                    m = fminf(m, acc[1][ni][1]); m = fminf(m, acc[1][ni][2]);
                    m = fminf(m, acc[1][ni][3]);
                    m = fminf(m, __shfl_xor(m, 16, 64));
                    m = fminf(m, __shfl_xor(m, 32, 64));
                    cm[ni] = m;
                }
                if (quad == 0) {
                    #pragma unroll
                    for (int ni = 0; ni < 4; ++ni) {
                        int col = n0 + wc + ni*16 + lc;
                        atomicMin(&bufL[rlo * EL + col], __float_as_uint(cm[ni]));
                    }
                }
            } else {
                for (int g = rlo; g <= rhi; ++g) {
                    float cm[4];
                    #pragma unroll
                    for (int ni = 0; ni < 4; ++ni) {
                        float m = FINF;
                        #pragma unroll
                        for (int mi = 0; mi < 2; ++mi)
                            #pragma unroll
                            for (int r = 0; r < 4; ++r)
                                m = fminf(m, (gr[mi*4 + r] == g) ? acc[mi][ni][r] : FINF);
                        m = fminf(m, __shfl_xor(m, 16, 64));
                        m = fminf(m, __shfl_xor(m, 32, 64));
                        cm[ni] = m;
                    }
                    if (quad == 0) {
                        #pragma unroll
                        for (int ni = 0; ni < 4; ++ni) {
                            int col = n0 + wc + ni*16 + lc;
                            atomicMin(&bufL[g * EL + col], __float_as_uint(cm[ni]));
                        }
                    }
                }
            }

            // reset accumulators for next col-tile
            #pragma unroll
            for (int i = 0; i < 2; ++i)
                #pragma unroll
                for (int j = 0; j < 4; ++j) {
                    f32x4 z = {0.f, 0.f, 0.f, 0.f};
                    acc[i][j] = z;
                }
        }
    }
}

// ---------------- kernel 3: segment means + combine ----------------
__device__ __forceinline__ int lbound(const int* __restrict__ a, int n, int v) {
    int lo = 0, hi = n;
    while (lo < hi) { int mid = (lo + hi) >> 1; if (a[mid] < v) lo = mid + 1; else hi = mid; }
    return lo;
}

// one block per node-graph gn; MUST be launched with 1024 threads
__global__ void finalize(const unsigned* __restrict__ bufN,
                         const unsigned* __restrict__ bufL,
                         const int* __restrict__ node_batch,
                         const int* __restrict__ label_batch,
                         float* __restrict__ out)
{
    __shared__ float sN[NG];   // sum over rows of -dist, per label graph
    __shared__ float sL[NG];   // sum over cols of -dist, per label graph
    int gn  = blockIdx.x;
    int tid = threadIdx.x;
    if (tid < NG) { sN[tid] = 0.0f; sL[tid] = 0.0f; }
    __syncthreads();

    int ns = lbound(node_batch, EN, gn);
    int ne = lbound(node_batch, EN, gn + 1);

    {
        int t = tid & 63, strip = tid >> 6;          // 16 row strips
        float acc = 0.0f;
        for (int i = ns + strip; i < ne; i += 16) {
            unsigned b = bufN[i * NG + t];
            if (b != INF_BITS) acc -= sqrtf(__uint_as_float(b));
        }
        atomicAdd(&sN[t], acc);
    }

    for (int j = tid; j < EL; j += 1024) {
        unsigned b = bufL[gn * EL + j];
        if (b != INF_BITS) {
            int g = label_batch[j];
            atomicAdd(&sL[g], -sqrtf(__uint_as_float(b)));
        }
    }
    __syncthreads();

    if (tid < NG) {
        int t = tid;
        int cn = ne - ns;
        int ls = lbound(label_batch, EL, t);
        int le = lbound(label_batch, EL, t + 1);
        int cl = le - ls;
        float out_n = sN[t] / (float)(cn > 0 ? cn : 1);
        float out_l = sL[t] / (float)(cl > 0 ? cl : 1);
        out[gn * NG + t] = 0.5f * (out_n + out_l);
    }
}

extern "C" void kernel_launch(void* const* d_in, const int* in_sizes, int n_in,
                              void* d_out, int out_size, void* d_ws, size_t ws_size,
                              hipStream_t stream)
{
    const float* h          = (const float*)d_in[0];
    const int* node_edge    = (const int*)d_in[1];
    const int* node_batch   = (const int*)d_in[2];
    const int* label_edge   = (const int*)d_in[3];
    const int* label_batch  = (const int*)d_in[4];
    float* out = (float*)d_out;

    char* ws = (char*)d_ws;
    unsigned short* efn = (unsigned short*)ws; ws += (size_t)EN * D * 2;
    unsigned short* efl = (unsigned short*)ws; ws += (size_t)EL * D * 2;
    float* normN = (float*)ws;                 ws += (size_t)EN * 4;
    float* normL = (float*)ws;                 ws += (size_t)EL * 4;
    unsigned* bufN = (unsigned*)ws;            ws += (size_t)EN * NG * 4;
    unsigned* bufL = (unsigned*)ws;            ws += (size_t)NG * EL * 4;

    // bufN,bufL contiguous: 1024 init blocks + 2048 + 2048 edge blocks
    prep<<<5120, 256, 0, stream>>>(h, node_edge, label_edge,
                                   efn, normN, efl, normL, bufN);
    dist_min<<<256, 512, 0, stream>>>(
        efn, efl, normN, normL, node_batch, label_batch, bufN, bufL);
    finalize<<<NG, 1024, 0, stream>>>(bufN, bufL, node_batch, label_batch, out);
}

// Round 11
// 194.918 us; speedup vs baseline: 1.1251x; 1.0303x over previous
//
#include <hip/hip_runtime.h>
#include <hip/hip_bf16.h>
#include <math.h>

#define EN 8192
#define EL 8192
#define D  256
#define NG 64
#define INF_BITS 0x7f800000u

typedef __attribute__((ext_vector_type(8))) short  bf16x8;
typedef __attribute__((ext_vector_type(4))) float  f32x4;

__device__ __forceinline__ unsigned short f2bf(float f) {
    unsigned u = __float_as_uint(f);
    unsigned r = (u + 0x7fffu + ((u >> 16) & 1u)) >> 16;   // RNE
    return (unsigned short)r;
}

// ---------------- kernel 1: edge features (init now via memset 0xFF) ----------------
// blocks [0,2048): node edges; [2048,4096): label edges
__global__ void prep(const float* __restrict__ h,
                     const int* __restrict__ node_edge,
                     const int* __restrict__ label_edge,
                     unsigned short* __restrict__ efn, float* __restrict__ normN,
                     unsigned short* __restrict__ efl, float* __restrict__ normL)
{
    int b = blockIdx.x;
    const int* edges; unsigned short* ef; float* norm;
    if (b < 2048) { edges = node_edge;  ef = efn; norm = normN; }
    else          { b -= 2048; edges = label_edge; ef = efl; norm = normL; }

    int wave = threadIdx.x >> 6;
    int lane = threadIdx.x & 63;
    int e = b * 4 + wave;
    int a  = edges[e];
    int bb = edges[EN + e];          // En == El == 8192
    float4 va = ((const float4*)(h + (size_t)a  * D))[lane];
    float4 vb = ((const float4*)(h + (size_t)bb * D))[lane];
    float4 f;
    f.x = 0.5f * (va.x + vb.x);
    f.y = 0.5f * (va.y + vb.y);
    f.z = 0.5f * (va.z + vb.z);
    f.w = 0.5f * (va.w + vb.w);
    float sq = f.x*f.x + f.y*f.y + f.z*f.z + f.w*f.w;
    ushort4 pk;
    pk.x = f2bf(f.x); pk.y = f2bf(f.y); pk.z = f2bf(f.z); pk.w = f2bf(f.w);
    ((ushort4*)(ef + (size_t)e * D))[lane] = pk;
    #pragma unroll
    for (int off = 1; off < 64; off <<= 1)
        sq += __shfl_xor(sq, off, 64);
    if (lane == 0) norm[e] = sq;
}

// ---------------- kernel 2: fused GEMM + sq-distance + segmented min ----------------
// Max-TLP variant of the verified R6 shape (every round's speed tracked
// resident waves, not pipeline depth: R4 27%/112us, R5 35%/104, R6 36%/92,
// R10 22%/104 — barrier-latency bound, nothing saturated):
//  * 1024 threads = 16 waves, wave-tile 16x64 (acc[1][4]); tile 128x128,
//    BK=64, 32 KB LDS. launch_bounds(1024,8): VGPR cap 64 (R6 compiled 44
//    with a larger live set), 2 blocks x 16 waves = 32 waves/CU = 100% cap —
//    one block's barrier drain overlaps the other's compute.
//  * XOR-swizzle (phys granule cc = logical ^ (row&7)) -> 0 conflicts
//    (verified R4/R5/R6/R9).
//  * Epilogue = verified R6 code with mi-loop collapsed to 1 (16-row wave
//    window; single-graph fast paths now P~0.89 row-side). Squared-dist min,
//    bulk atomics, sqrt deferred. Min-buffers init to 0xFFFFFFFF by memset;
//    unsigned atomicMin on positive-float bits unaffected; finalize skips
//    b >= INF_BITS.
__launch_bounds__(1024, 8)
__global__ void dist_min(const unsigned short* __restrict__ A,   // ef_n [EN][D]
                         const unsigned short* __restrict__ B,   // ef_l [EL][D]
                         const float* __restrict__ normN,
                         const float* __restrict__ normL,
                         const int* __restrict__ node_batch,
                         const int* __restrict__ label_batch,
                         unsigned* __restrict__ bufN,  // [EN][NG] min sq-dist bits
                         unsigned* __restrict__ bufL)  // [NG][EL] min sq-dist bits
{
    __shared__ unsigned short As[128 * 64];
    __shared__ unsigned short Bs[128 * 64];

    const int tid  = threadIdx.x;
    const int lane = tid & 63;
    const int wave = tid >> 6;          // 0..15
    const int quad = lane >> 4;
    const int lc   = lane & 15;
    const int m0   = blockIdx.y * 128;
    const int n0   = blockIdx.x * 128;
    const int wr   = (wave >> 1) * 16;  // 8 row groups of 16
    const int wc   = (wave & 1) * 64;   // 2 col groups of 64

    f32x4 acc[4];
    #pragma unroll
    for (int j = 0; j < 4; ++j) {
        f32x4 z = {0.f, 0.f, 0.f, 0.f};
        acc[j] = z;
    }

    for (int kt = 0; kt < 4; ++kt) {            // K = 256 = 4 * 64
        // stage tiles: 1024 granules each, 1 per thread; phys chunk cc holds
        // global chunk cc^(row&7)
        {
            int row = tid >> 3, cc = tid & 7;
            int scc = cc ^ (row & 7);
            const unsigned short* gp = A + (size_t)(m0 + row) * D + kt * 64 + scc * 8;
            __builtin_amdgcn_global_load_lds(
                (const __attribute__((address_space(1))) void*)gp,
                (__attribute__((address_space(3))) void*)(As + tid * 8), 16, 0, 0);
            gp = B + (size_t)(n0 + row) * D + kt * 64 + scc * 8;
            __builtin_amdgcn_global_load_lds(
                (const __attribute__((address_space(1))) void*)gp,
                (__attribute__((address_space(3))) void*)(Bs + tid * 8), 16, 0, 0);
        }
        __syncthreads();

        #pragma unroll
        for (int kk = 0; kk < 2; ++kk) {        // two k=32 steps
            bf16x8 af, bfv[4];
            af = *(const bf16x8*)(As + (wr + lc) * 64
                                     + ((kk*4 + quad) ^ (lc & 7)) * 8);
            #pragma unroll
            for (int ni = 0; ni < 4; ++ni)
                bfv[ni] = *(const bf16x8*)(Bs + (wc + ni*16 + lc) * 64
                                              + ((kk*4 + quad) ^ (lc & 7)) * 8);
            #pragma unroll
            for (int ni = 0; ni < 4; ++ni)
                acc[ni] = __builtin_amdgcn_mfma_f32_16x16x32_bf16(
                    af, bfv[ni], acc[ni], 0, 0, 0);
        }
        __syncthreads();
    }

    // ---- epilogue (verified R6, mi collapsed) ----
    float nb[4]; int gl[4];
    #pragma unroll
    for (int ni = 0; ni < 4; ++ni) {
        int col = n0 + wc + ni*16 + lc;
        nb[ni] = normL[col];
        gl[ni] = label_batch[col];
    }
    float na[4]; int gr[4];
    #pragma unroll
    for (int r = 0; r < 4; ++r) {
        int row = m0 + wr + quad*4 + r;
        na[r] = normN[row];
        gr[r] = node_batch[row];
    }

    #pragma unroll
    for (int ni = 0; ni < 4; ++ni)
        #pragma unroll
        for (int r = 0; r < 4; ++r)
            acc[ni][r] = fmaxf(fmaf(-2.0f, acc[ni][r], na[r] + nb[ni]), 0.0f);

    const float FINF = __uint_as_float(INF_BITS);

    // per-row min over columns, grouped by label graph; wave cols [n0+wc, +63]
    int glo = label_batch[n0 + wc], ghi = label_batch[n0 + wc + 63];
    if (glo == ghi) {
        float rm[4];
        #pragma unroll
        for (int r = 0; r < 4; ++r) {
            float m = fminf(fminf(acc[0][r], acc[1][r]),
                            fminf(acc[2][r], acc[3][r]));
            m = fminf(m, __shfl_xor(m, 1, 64));
            m = fminf(m, __shfl_xor(m, 2, 64));
            m = fminf(m, __shfl_xor(m, 4, 64));
            m = fminf(m, __shfl_xor(m, 8, 64));
            rm[r] = m;
        }
        if (lc == 0) {
            #pragma unroll
            for (int r = 0; r < 4; ++r) {
                int row = m0 + wr + quad*4 + r;
                atomicMin(&bufN[row * NG + glo], __float_as_uint(rm[r]));
            }
        }
    } else {
        for (int g = glo; g <= ghi; ++g) {
            bool s0 = (gl[0] == g), s1 = (gl[1] == g), s2 = (gl[2] == g), s3 = (gl[3] == g);
            float rm[4];
            #pragma unroll
            for (int r = 0; r < 4; ++r) {
                float m = s0 ? acc[0][r] : FINF;
                m = fminf(m, s1 ? acc[1][r] : FINF);
                m = fminf(m, s2 ? acc[2][r] : FINF);
                m = fminf(m, s3 ? acc[3][r] : FINF);
                m = fminf(m, __shfl_xor(m, 1, 64));
                m = fminf(m, __shfl_xor(m, 2, 64));
                m = fminf(m, __shfl_xor(m, 4, 64));
                m = fminf(m, __shfl_xor(m, 8, 64));
                rm[r] = m;
            }
            if (lc == 0) {
                #pragma unroll
                for (int r = 0; r < 4; ++r) {
                    int row = m0 + wr + quad*4 + r;
                    atomicMin(&bufN[row * NG + g], __float_as_uint(rm[r]));
                }
            }
        }
    }

    // per-col min over rows, grouped by node graph; wave rows [m0+wr, +15]
    int rlo = node_batch[m0 + wr], rhi = node_batch[m0 + wr + 15];
    if (rlo == rhi) {
        float cm[4];
        #pragma unroll
        for (int ni = 0; ni < 4; ++ni) {
            float m = fminf(fminf(acc[ni][0], acc[ni][1]),
                            fminf(acc[ni][2], acc[ni][3]));
            m = fminf(m, __shfl_xor(m, 16, 64));
            m = fminf(m, __shfl_xor(m, 32, 64));
            cm[ni] = m;
        }
        if (quad == 0) {
            #pragma unroll
            for (int ni = 0; ni < 4; ++ni) {
                int col = n0 + wc + ni*16 + lc;
                atomicMin(&bufL[rlo * EL + col], __float_as_uint(cm[ni]));
            }
        }
    } else {
        for (int g = rlo; g <= rhi; ++g) {
            float cm[4];
            #pragma unroll
            for (int ni = 0; ni < 4; ++ni) {
                float m = FINF;
                #pragma unroll
                for (int r = 0; r < 4; ++r)
                    m = fminf(m, (gr[r] == g) ? acc[ni][r] : FINF);
                m = fminf(m, __shfl_xor(m, 16, 64));
                m = fminf(m, __shfl_xor(m, 32, 64));
                cm[ni] = m;
            }
            if (quad == 0) {
                #pragma unroll
                for (int ni = 0; ni < 4; ++ni) {
                    int col = n0 + wc + ni*16 + lc;
                    atomicMin(&bufL[g * EL + col], __float_as_uint(cm[ni]));
                }
            }
        }
    }
}

// ---------------- kernel 3: segment means + combine ----------------
__device__ __forceinline__ int lbound(const int* __restrict__ a, int n, int v) {
    int lo = 0, hi = n;
    while (lo < hi) { int mid = (lo + hi) >> 1; if (a[mid] < v) lo = mid + 1; else hi = mid; }
    return lo;
}

// one block per node-graph gn; MUST be launched with 1024 threads.
// Sentinel: buffers memset to 0xFFFFFFFF; any written sq-dist is a finite
// positive float (bits < INF_BITS); slow-path may write INF_BITS for empty
// segments -> skip all b >= INF_BITS.
__global__ void finalize(const unsigned* __restrict__ bufN,
                         const unsigned* __restrict__ bufL,
                         const int* __restrict__ node_batch,
                         const int* __restrict__ label_batch,
                         float* __restrict__ out)
{
    __shared__ float sN[NG];   // sum over rows of -dist, per label graph
    __shared__ float sL[NG];   // sum over cols of -dist, per label graph
    int gn  = blockIdx.x;
    int tid = threadIdx.x;
    if (tid < NG) { sN[tid] = 0.0f; sL[tid] = 0.0f; }
    __syncthreads();

    int ns = lbound(node_batch, EN, gn);
    int ne = lbound(node_batch, EN, gn + 1);

    {
        int t = tid & 63, strip = tid >> 6;          // 16 row strips
        float acc = 0.0f;
        for (int i = ns + strip; i < ne; i += 16) {
            unsigned b = bufN[i * NG + t];
            if (b < INF_BITS) acc -= sqrtf(__uint_as_float(b));
        }
        atomicAdd(&sN[t], acc);
    }

    for (int j = tid; j < EL; j += 1024) {
        unsigned b = bufL[gn * EL + j];
        if (b < INF_BITS) {
            int g = label_batch[j];
            atomicAdd(&sL[g], -sqrtf(__uint_as_float(b)));
        }
    }
    __syncthreads();

    if (tid < NG) {
        int t = tid;
        int cn = ne - ns;
        int ls = lbound(label_batch, EL, t);
        int le = lbound(label_batch, EL, t + 1);
        int cl = le - ls;
        float out_n = sN[t] / (float)(cn > 0 ? cn : 1);
        float out_l = sL[t] / (float)(cl > 0 ? cl : 1);
        out[gn * NG + t] = 0.5f * (out_n + out_l);
    }
}

extern "C" void kernel_launch(void* const* d_in, const int* in_sizes, int n_in,
                              void* d_out, int out_size, void* d_ws, size_t ws_size,
                              hipStream_t stream)
{
    const float* h          = (const float*)d_in[0];
    const int* node_edge    = (const int*)d_in[1];
    const int* node_batch   = (const int*)d_in[2];
    const int* label_edge   = (const int*)d_in[3];
    const int* label_batch  = (const int*)d_in[4];
    float* out = (float*)d_out;

    char* ws = (char*)d_ws;
    unsigned short* efn = (unsigned short*)ws; ws += (size_t)EN * D * 2;
    unsigned short* efl = (unsigned short*)ws; ws += (size_t)EL * D * 2;
    float* normN = (float*)ws;                 ws += (size_t)EN * 4;
    float* normL = (float*)ws;                 ws += (size_t)EL * 4;
    unsigned* bufN = (unsigned*)ws;            ws += (size_t)EN * NG * 4;
    unsigned* bufL = (unsigned*)ws;            ws += (size_t)NG * EL * 4;

    // bufN,bufL contiguous: init to 0xFFFFFFFF sentinel via async memset
    hipMemsetAsync(bufN, 0xFF, (size_t)(EN * NG + NG * EL) * 4, stream);
    prep<<<4096, 256, 0, stream>>>(h, node_edge, label_edge,
                                   efn, normN, efl, normL);
    dist_min<<<dim3(EL / 128, EN / 128), 1024, 0, stream>>>(
        efn, efl, normN, normL, node_batch, label_batch, bufN, bufL);
    finalize<<<NG, 1024, 0, stream>>>(bufN, bufL, node_batch, label_batch, out);
}